// Round 7
// baseline (10050.586 us; speedup 1.0000x reference)
//
#include <hip/hip_runtime.h>
#include <math.h>

// ---------------- problem constants ----------------
#define NEDU  1024
#define LTOK  20
#define CW    330     // 300 word + 30 pos
#define HDIM  256
#define FEAT  930
#define MSLOT 1026    // N_EDUS + 2
#define NWG   64      // parse workgroups; WG bx owns h-indices 4bx..4bx+3

typedef unsigned long long u64;

// ---------------- workspace layout (32-bit word offsets) ----------------
#define O_WCATT 0
#define SZ_WCATT (330*600)
#define O_F     (O_WCATT + SZ_WCATT)
#define SZ_F    (NEDU*FEAT)
#define O_BUFH  (O_F + SZ_F)
#define SZ_BUF  (MSLOT*HDIM)
#define O_BUFC  (O_BUFH + SZ_BUF)
#define O_STKT  (O_BUFC + SZ_BUF)          // tagged stack_h [slot][j] u32
#define O_THT   (O_STKT + MSLOT*HDIM)      // tagged tracker h, 2 parities
#define O_RHT   (O_THT + 2*HDIM)           // tagged compose rh
#define O_LOSSP (O_RHT + HDIM)             // loss partials [2048][128] float
#define NZERO   ((MSLOT + 3) * HDIM)       // stkT + thT(2) + rhT -> zeros w/ tag 0

#define AG __HIP_MEMORY_SCOPE_AGENT
__device__ __forceinline__ u64 aload64(const u64* p) {
  return __hip_atomic_load(p, __ATOMIC_RELAXED, AG);
}
__device__ __forceinline__ void astore(unsigned* p, unsigned v) {
  __hip_atomic_store(p, v, __ATOMIC_RELAXED, AG);
}
__device__ __forceinline__ unsigned tagbits(float v, unsigned ver) {
  return (__float_as_uint(v) & ~3u) | (ver & 3u);
}
__device__ __forceinline__ bool tagok(u64 v, unsigned tag) {
  return (((unsigned)v & 3u) == tag) & (((unsigned)(v >> 32) & 3u) == tag);
}
__device__ __forceinline__ float sigm(float x) { return 1.f / (1.f + expf(-x)); }
__device__ __forceinline__ void unpack(u64 a, u64 b, float* x) {
  x[0] = __uint_as_float((unsigned)a); x[1] = __uint_as_float((unsigned)(a >> 32));
  x[2] = __uint_as_float((unsigned)b); x[3] = __uint_as_float((unsigned)(b >> 32));
}
// raw WG barrier: waits LDS ops only, NOT vmem stores (no vmcnt drain)
__device__ __forceinline__ void sync_lds() {
  asm volatile("s_waitcnt lgkmcnt(0)\n\ts_barrier" ::: "memory");
}

// staged gathers: iteration 1 issues ALL loads in parallel (one round trip);
// once a vector's tags pass it is unpacked and never re-loaded; steady-state
// spin polls ONLY the fresh vector (16 B/lane).
__device__ __forceinline__ void gatherF1S1(const unsigned* fb, unsigned ft,
                                           const unsigned* s1, unsigned t1,
                                           int lane, float* xf, float* x1) {
  const u64* pf = (const u64*)fb + 2 * lane;
  const u64* p1 = (const u64*)s1 + 2 * lane;
  bool d1 = false;
  for (int it = 0;; ++it) {
    const u64 fa = aload64(pf), fb2 = aload64(pf + 1);
    if (!d1) {
      const u64 a = aload64(p1), b = aload64(p1 + 1);
      if (__ballot(tagok(a, t1) & tagok(b, t1)) == ~0ull) { unpack(a, b, x1); d1 = true; }
    }
    if (d1 && (__ballot(tagok(fa, ft) & tagok(fb2, ft)) == ~0ull)) {
      unpack(fa, fb2, xf); return;
    }
    if (it > 16) __builtin_amdgcn_s_sleep(1);
  }
}
__device__ __forceinline__ void gatherF1S2(const unsigned* fb, unsigned ft,
                                           const unsigned* s1, unsigned t1,
                                           const unsigned* s2, unsigned t2,
                                           int lane, float* xf, float* x1, float* x2) {
  const u64* pf = (const u64*)fb + 2 * lane;
  const u64* p1 = (const u64*)s1 + 2 * lane;
  const u64* p2 = (const u64*)s2 + 2 * lane;
  bool d1 = false, d2 = false;
  for (int it = 0;; ++it) {
    const u64 fa = aload64(pf), fb2 = aload64(pf + 1);
    if (!d1) {
      const u64 a = aload64(p1), b = aload64(p1 + 1);
      if (__ballot(tagok(a, t1) & tagok(b, t1)) == ~0ull) { unpack(a, b, x1); d1 = true; }
    }
    if (!d2) {
      const u64 a = aload64(p2), b = aload64(p2 + 1);
      if (__ballot(tagok(a, t2) & tagok(b, t2)) == ~0ull) { unpack(a, b, x2); d2 = true; }
    }
    if (d1 && d2 && (__ballot(tagok(fa, ft) & tagok(fb2, ft)) == ~0ull)) {
      unpack(fa, fb2, xf); return;
    }
    if (it > 16) __builtin_amdgcn_s_sleep(1);
  }
}

// ---------------- prep: weight transpose + zeroing ----------------
__global__ void prep_kernel(const float* __restrict__ Wu, const float* __restrict__ Wb,
                            const float* __restrict__ Wt, float* __restrict__ ws) {
  const int i0 = blockIdx.x * blockDim.x + threadIdx.x;
  const int st = gridDim.x * blockDim.x;
  for (int i = i0; i < SZ_WCATT; i += st) {
    const int k = i / 600, c = i - 600 * k;
    float v;
    if (c < 100)      v = Wu[c * 330 + k];
    else if (c < 300) { const int q = c - 100; v = Wb[(q % 100) * 660 + (q / 100) * 330 + k]; }
    else              { const int q = c - 300; v = Wt[(q % 100) * 990 + (q / 100) * 330 + k]; }
    ws[O_WCATT + i] = v;
  }
  unsigned* z = (unsigned*)ws + O_STKT;
  for (int i = i0; i < NZERO; i += st) z[i] = 0u;              // zeros with ver-0 tags
  for (int i = i0; i < 2 * HDIM; i += st) {                    // buf zero rows 1024,1025
    ws[O_BUFH + NEDU * HDIM + i] = 0.f;
    ws[O_BUFC + NEDU * HDIM + i] = 0.f;
  }
}

// ---------------- encode (unchanged) ----------------
__global__ __launch_bounds__(256) void encode_kernel(
    const int* __restrict__ edu_words, const int* __restrict__ edu_poses,
    const float* __restrict__ word_emb, const float* __restrict__ pos_emb,
    const float* __restrict__ bu, const float* __restrict__ bb,
    const float* __restrict__ bt, float* __restrict__ ws) {
  __shared__ __align__(16) float xlT[CW * LTOK];
  __shared__ float zl[300 * 21];
  __shared__ float convout[300];
  const int n = blockIdx.x, tid = threadIdx.x;
  const float* WcatT = ws + O_WCATT;

  for (int i = tid; i < LTOK * CW; i += 256) {
    const int l = i / CW, k = i - l * CW;
    float v;
    if (k < 300) v = word_emb[(size_t)edu_words[n * LTOK + l] * 300 + k];
    else         v = pos_emb[(size_t)edu_poses[n * LTOK + l] * 30 + (k - 300)];
    xlT[k * LTOK + l] = v;
  }
  __syncthreads();

  for (int f = tid; f < 300; f += 256) {
    float acc[LTOK];
#pragma unroll
    for (int l = 0; l < LTOK; ++l) acc[l] = 0.f;
    for (int k = 0; k < CW; ++k) {
      const float w = WcatT[k * 600 + f];
      const float4* xp = (const float4*)(xlT + k * LTOK);
      union { float4 v[5]; float s[20]; } xu;
      xu.v[0] = xp[0]; xu.v[1] = xp[1]; xu.v[2] = xp[2]; xu.v[3] = xp[3]; xu.v[4] = xp[4];
#pragma unroll
      for (int l = 0; l < LTOK; ++l) acc[l] += w * xu.s[l];
    }
#pragma unroll
    for (int l = 0; l < LTOK; ++l) zl[f * 21 + l] = acc[l];
  }
  __syncthreads();
  if (tid < 200) {
    float m;
    if (tid < 100) {
      const int f = tid; const float b = bu[f];
      m = zl[f * 21] + b;
      for (int l = 1; l < 20; ++l) m = fmaxf(m, zl[f * 21 + l] + b);
    } else {
      const int f = tid - 100; const float b = bb[f];
      const float* z0 = zl + (100 + f) * 21;
      const float* z1 = zl + (200 + f) * 21;
      m = z1[0] + b;
      for (int u = 1; u <= 19; ++u) m = fmaxf(m, z0[u - 1] + z1[u] + b);
      m = fmaxf(m, z0[19] + b);
    }
    convout[tid] = fmaxf(m, 0.f);
  }
  __syncthreads();

  for (int f = tid; f < 300; f += 256) {
    float acc[LTOK];
#pragma unroll
    for (int l = 0; l < LTOK; ++l) acc[l] = 0.f;
    for (int k = 0; k < CW; ++k) {
      const float w = WcatT[k * 600 + 300 + f];
      const float4* xp = (const float4*)(xlT + k * LTOK);
      union { float4 v[5]; float s[20]; } xu;
      xu.v[0] = xp[0]; xu.v[1] = xp[1]; xu.v[2] = xp[2]; xu.v[3] = xp[3]; xu.v[4] = xp[4];
#pragma unroll
      for (int l = 0; l < LTOK; ++l) acc[l] += w * xu.s[l];
    }
#pragma unroll
    for (int l = 0; l < LTOK; ++l) zl[f * 21 + l] = acc[l];
  }
  __syncthreads();
  if (tid < 100) {
    const int f = tid; const float b = bt[f];
    const float* z0 = zl + f * 21;
    const float* z1 = zl + (100 + f) * 21;
    const float* z2 = zl + (200 + f) * 21;
    float m = z2[0] + b;
    m = fmaxf(m, z1[0] + z2[1] + b);
    for (int u = 2; u <= 19; ++u) m = fmaxf(m, z0[u - 2] + z1[u - 1] + z2[u] + b);
    m = fmaxf(m, z0[18] + z1[19] + b);
    m = fmaxf(m, z0[19] + b);
    convout[200 + f] = fmaxf(m, 0.f);
  }
  __syncthreads();

  float* Fr = ws + O_F + (size_t)n * FEAT;
  for (int j = tid; j < FEAT; j += 256) {
    float v;
    if (j < 300)      v = xlT[j * LTOK + 0];
    else if (j < 600) v = xlT[(j - 300) * LTOK + 19];
    else if (j < 630) v = xlT[(j - 300) * LTOK + 0];
    else              v = convout[j - 630];
    Fr[j] = v;
  }
}

// ---------------- proj (unchanged) ----------------
__global__ __launch_bounds__(256) void proj_kernel(const float* __restrict__ Wp,
                                                   const float* __restrict__ bp,
                                                   float* __restrict__ ws) {
  __shared__ float As[64][17];
  __shared__ float Bs[64][17];
  const float* F = ws + O_F;
  float* bufh = ws + O_BUFH;
  float* bufc = ws + O_BUFC;
  const int tid = threadIdx.x;
  const int m0 = blockIdx.x * 64, n0 = blockIdx.y * 64;
  const int mm0 = (tid & 15) * 4, nn0 = (tid >> 4) * 4;
  float acc[4][4] = {{0.f}};
  for (int k0 = 0; k0 < FEAT; k0 += 16) {
    for (int i = tid; i < 64 * 16; i += 256) {
      const int mm = i >> 4, kk = i & 15;
      const int gk = k0 + kk;
      As[mm][kk] = (gk < FEAT) ? F[(size_t)(m0 + mm) * FEAT + gk] : 0.f;
      Bs[mm][kk] = (gk < FEAT) ? Wp[(size_t)(n0 + mm) * FEAT + gk] : 0.f;
    }
    __syncthreads();
#pragma unroll
    for (int kk = 0; kk < 16; ++kk) {
      float av[4], bv[4];
#pragma unroll
      for (int i = 0; i < 4; ++i) av[i] = As[mm0 + i][kk];
#pragma unroll
      for (int j = 0; j < 4; ++j) bv[j] = Bs[nn0 + j][kk];
#pragma unroll
      for (int i = 0; i < 4; ++i)
#pragma unroll
        for (int j = 0; j < 4; ++j) acc[i][j] += av[i] * bv[j];
    }
    __syncthreads();
  }
#pragma unroll
  for (int i = 0; i < 4; ++i) {
    const int m = m0 + mm0 + i;
#pragma unroll
    for (int j = 0; j < 4; ++j) {
      const int nn = n0 + nn0 + j;
      const float v = acc[i][j] + bp[nn];
      if (nn < 256) bufh[(size_t)m * 256 + nn] = v;
      else          bufc[(size_t)m * 256 + (nn - 256)] = v;
    }
  }
}

// ---------------- parse: staged tagged dataflow, 1 round trip / sub-stage ----------------
__global__ __launch_bounds__(256, 1) void parse_kernel(
    const int* __restrict__ transes, int nT,
    const float* __restrict__ Wih, const float* __restrict__ Whh,
    const float* __restrict__ bih, const float* __restrict__ bhh,
    const float* __restrict__ Wc, const float* __restrict__ bc,
    const float* __restrict__ Wsc, float* __restrict__ ws) {
  const int tid = threadIdx.x;
  const int lane = tid & 63;
  const int wv = tid >> 6;
  const int bx = blockIdx.x;
  const int j0 = bx * 4;

  const float* bufh = ws + O_BUFH;
  const float* bufc = ws + O_BUFC;
  unsigned* stkT = (unsigned*)ws + O_STKT;
  unsigned* thT  = (unsigned*)ws + O_THT;
  unsigned* rhT  = (unsigned*)ws + O_RHT;
  float* lossp   = ws + O_LOSSP;

  __shared__ float sc_lds[MSLOT][4];   // private stack-c for owned h-indices
  __shared__ unsigned vstk[MSLOT];     // per-slot version table (WG-uniform)
  __shared__ float g_lds[20];          // gate staging
  __shared__ float part_lds[8];        // loss partial staging

  // ---- weight slices (element e = 4*lane + c) ----
  float wt[4][16]; float bt_[4];
#pragma unroll
  for (int q = 0; q < 4; ++q) {
    const int rg = wv * 256 + j0 + q;
#pragma unroll
    for (int blk = 0; blk < 3; ++blk) {
      const float4 w = *(const float4*)(Wih + (size_t)rg * 768 + blk * 256 + 4 * lane);
      wt[q][4 * blk + 0] = w.x; wt[q][4 * blk + 1] = w.y;
      wt[q][4 * blk + 2] = w.z; wt[q][4 * blk + 3] = w.w;
    }
    const float4 wh = *(const float4*)(Whh + (size_t)rg * 256 + 4 * lane);
    wt[q][12] = wh.x; wt[q][13] = wh.y; wt[q][14] = wh.z; wt[q][15] = wh.w;
    bt_[q] = bih[rg] + bhh[rg];
  }
  float wcm[5][12]; float bc_[5];
#pragma unroll
  for (int q = 0; q < 5; ++q) {
    const int row = 5 * wv + q, gate = row >> 2, jj = row & 3;
    const int rg = gate * 256 + j0 + jj;
#pragma unroll
    for (int blk = 0; blk < 3; ++blk) {
      const float4 w = *(const float4*)(Wc + (size_t)rg * 768 + blk * 256 + 4 * lane);
      wcm[q][4 * blk + 0] = w.x; wcm[q][4 * blk + 1] = w.y;
      wcm[q][4 * blk + 2] = w.z; wcm[q][4 * blk + 3] = w.w;
    }
    bc_[q] = bc[rg];
  }
  float ws0 = 0.f, ws1 = 0.f;
  if (tid < 4) { ws0 = Wsc[j0 + tid]; ws1 = Wsc[256 + j0 + tid]; }

  for (int i = tid; i < MSLOT; i += 256) vstk[i] = 0u;
  if (tid < 4) { sc_lds[0][tid] = 0.f; sc_lds[1][tid] = 0.f; }
  __syncthreads();

  unsigned V = 0, vrh = 0;
  int sptr = 2, bptr = 0;
  float tc_reg = 0.f;     // tracker c (lanes 0-3 of wave0)
  float rh_reg = 0.f;     // compose rh (lanes 0-3 of wave0)
  float xth[4];           // th(V) cached at compose for trackR reuse

  auto red4 = [&](float& a0, float& a1, float& a2, float& a3) {
#pragma unroll
    for (int off = 32; off; off >>= 1) {
      a0 += __shfl_down(a0, off, 64); a1 += __shfl_down(a1, off, 64);
      a2 += __shfl_down(a2, off, 64); a3 += __shfl_down(a3, off, 64);
    }
  };
  auto red5 = [&](float& a0, float& a1, float& a2, float& a3, float& a4) {
#pragma unroll
    for (int off = 32; off; off >>= 1) {
      a0 += __shfl_down(a0, off, 64); a1 += __shfl_down(a1, off, 64);
      a2 += __shfl_down(a2, off, 64); a3 += __shfl_down(a3, off, 64);
      a4 += __shfl_down(a4, off, 64);
    }
  };

  // shared track tail: reduce -> g_lds -> ONE barrier -> fin (tid<4) -> loss
  auto tail_track = [&](float d0, float d1, float d2, float d3) {
    red4(d0, d1, d2, d3);
    if (lane == 0) {
      g_lds[wv * 4 + 0] = d0 + bt_[0]; g_lds[wv * 4 + 1] = d1 + bt_[1];
      g_lds[wv * 4 + 2] = d2 + bt_[2]; g_lds[wv * 4 + 3] = d3 + bt_[3];
    }
    sync_lds();
    if (tid < 4) {
      const int j = j0 + tid;
      const float gi = g_lds[tid], gf = g_lds[4 + tid], gg = g_lds[8 + tid],
                  go = g_lds[12 + tid];
      const float cn = sigm(gf) * tc_reg + sigm(gi) * tanhf(gg);
      tc_reg = cn;
      const float th = sigm(go) * tanhf(cn);
      astore(thT + ((V + 1) & 1) * HDIM + j, tagbits(th, V + 1));
      part_lds[tid] = ws0 * th; part_lds[4 + tid] = ws1 * th;
    }
    if (tid == 0) {
      float* lp = lossp + (size_t)V * 128 + bx * 2;
      lp[0] = part_lds[0] + part_lds[1] + part_lds[2] + part_lds[3];
      lp[1] = part_lds[4] + part_lds[5] + part_lds[6] + part_lds[7];
    }
    V += 1;
    // no trailing barrier: next sub-stage's g_lds writes are gated on th/rh
    // visibility, which requires this fin to have completed.
  };

  // ---- initial track: statics stack[1],stack[0] (v0); fresh th(v0) ----
  {
    const float4 f3 = *(const float4*)(bufh + 4 * lane);
    float p1[4], p2[4], xf[4];
    gatherF1S2(thT, 0u, stkT + HDIM, 0u, stkT, 0u, lane, xf, p1, p2);
    const float p3[4] = { f3.x, f3.y, f3.z, f3.w };
    float d0 = 0.f, d1 = 0.f, d2 = 0.f, d3 = 0.f;
#pragma unroll
    for (int c = 0; c < 4; ++c) {
      d0 += wt[0][c]*p1[c] + wt[0][4+c]*p2[c] + wt[0][8+c]*p3[c] + wt[0][12+c]*xf[c];
      d1 += wt[1][c]*p1[c] + wt[1][4+c]*p2[c] + wt[1][8+c]*p3[c] + wt[1][12+c]*xf[c];
      d2 += wt[2][c]*p1[c] + wt[2][4+c]*p2[c] + wt[2][8+c]*p3[c] + wt[2][12+c]*xf[c];
      d3 += wt[3][c]*p1[c] + wt[3][4+c]*p2[c] + wt[3][8+c]*p3[c] + wt[3][12+c]*xf[c];
    }
    tail_track(d0, d1, d2, d3);
  }

  for (int t = 0; t < nT; ++t) {
    const int tr = transes[t];
    if (tr) {
      // ==== compose: staged gather (statics h1,h2; fresh th) ====
      {
        float h1[4], h2[4];
        gatherF1S2(thT + (V & 1) * HDIM, V & 3,
                   stkT + (size_t)(sptr - 1) * HDIM, vstk[sptr - 1] & 3,
                   stkT + (size_t)(sptr - 2) * HDIM, vstk[sptr - 2] & 3,
                   lane, xth, h1, h2);
        float e0 = 0.f, e1 = 0.f, e2 = 0.f, e3 = 0.f, e4 = 0.f;
#pragma unroll
        for (int c = 0; c < 4; ++c) {
          e0 += wcm[0][c]*h1[c] + wcm[0][4+c]*h2[c] + wcm[0][8+c]*xth[c];
          e1 += wcm[1][c]*h1[c] + wcm[1][4+c]*h2[c] + wcm[1][8+c]*xth[c];
          e2 += wcm[2][c]*h1[c] + wcm[2][4+c]*h2[c] + wcm[2][8+c]*xth[c];
          e3 += wcm[3][c]*h1[c] + wcm[3][4+c]*h2[c] + wcm[3][8+c]*xth[c];
          e4 += wcm[4][c]*h1[c] + wcm[4][4+c]*h2[c] + wcm[4][8+c]*xth[c];
        }
        red5(e0, e1, e2, e3, e4);
        if (lane == 0) {
          g_lds[5 * wv + 0] = e0 + bc_[0]; g_lds[5 * wv + 1] = e1 + bc_[1];
          g_lds[5 * wv + 2] = e2 + bc_[2]; g_lds[5 * wv + 3] = e3 + bc_[3];
          g_lds[5 * wv + 4] = e4 + bc_[4];
        }
        sync_lds();
        if (tid < 4) {
          const float ga = g_lds[tid], gi = g_lds[4 + tid], gf1 = g_lds[8 + tid],
                      gf2 = g_lds[12 + tid], go = g_lds[16 + tid];
          const float c1 = sc_lds[sptr - 1][tid];
          const float c2 = sc_lds[sptr - 2][tid];
          const float rc = tanhf(ga) * sigm(gi) + sigm(gf1) * c1 + sigm(gf2) * c2;
          sc_lds[sptr - 2][tid] = rc;
          rh_reg = sigm(go) * tanhf(rc);
          astore(rhT + j0 + tid, tagbits(rh_reg, vrh + 1));
        }
        vrh += 1;
        // no trailing barrier (trackR g_lds writes gated on rh visibility)
      }
      // ==== trackR: staged gather (static stack[sptr-3]; fresh rh); th cached ====
      {
        const float4 f3 = *(const float4*)(bufh + (size_t)bptr * HDIM + 4 * lane);
        float pr[4], p2[4];
        gatherF1S1(rhT, vrh & 3,
                   stkT + (size_t)(sptr - 3) * HDIM, vstk[sptr - 3] & 3, lane, pr, p2);
        // deferred stack write: rh(vrh) fully visible => every WG finished its
        // compose compute => all compose reads of slot sptr-2 are done. Safe.
        __atomic_signal_fence(__ATOMIC_SEQ_CST);
        const unsigned nv2 = vstk[sptr - 2] + 1;
        if (tid < 4) astore(stkT + (size_t)(sptr - 2) * HDIM + j0 + tid,
                            tagbits(rh_reg, nv2));
        if (tid == 0) vstk[sptr - 2] = nv2;   // read only after the tail barrier
        const float p3[4] = { f3.x, f3.y, f3.z, f3.w };
        float d0 = 0.f, d1 = 0.f, d2 = 0.f, d3 = 0.f;
#pragma unroll
        for (int c = 0; c < 4; ++c) {
          d0 += wt[0][c]*pr[c] + wt[0][4+c]*p2[c] + wt[0][8+c]*p3[c] + wt[0][12+c]*xth[c];
          d1 += wt[1][c]*pr[c] + wt[1][4+c]*p2[c] + wt[1][8+c]*p3[c] + wt[1][12+c]*xth[c];
          d2 += wt[2][c]*pr[c] + wt[2][4+c]*p2[c] + wt[2][8+c]*p3[c] + wt[2][12+c]*xth[c];
          d3 += wt[3][c]*pr[c] + wt[3][4+c]*p2[c] + wt[3][8+c]*p3[c] + wt[3][12+c]*xth[c];
        }
        tail_track(d0, d1, d2, d3);
        sptr -= 1;
      }
    } else {
      // ==== trackS: early push; staged gather (static stack[sptr-1]; fresh th) ====
      const unsigned nv = vstk[sptr] + 1;
      if (tid < 4) {
        const int j = j0 + tid;
        astore(stkT + (size_t)sptr * HDIM + j, tagbits(bufh[(size_t)bptr * HDIM + j], nv));
        sc_lds[sptr][tid] = bufc[(size_t)bptr * HDIM + j];
      }
      if (tid == 0) vstk[sptr] = nv;          // read only after the tail barrier
      const float4 f1 = *(const float4*)(bufh + (size_t)bptr * HDIM + 4 * lane);
      const float4 f3 = *(const float4*)(bufh + (size_t)(bptr + 1) * HDIM + 4 * lane);
      float p2[4], xf[4];
      gatherF1S1(thT + (V & 1) * HDIM, V & 3,
                 stkT + (size_t)(sptr - 1) * HDIM, vstk[sptr - 1] & 3, lane, xf, p2);
      const float p1[4] = { f1.x, f1.y, f1.z, f1.w };
      const float p3[4] = { f3.x, f3.y, f3.z, f3.w };
      float d0 = 0.f, d1 = 0.f, d2 = 0.f, d3 = 0.f;
#pragma unroll
      for (int c = 0; c < 4; ++c) {
        d0 += wt[0][c]*p1[c] + wt[0][4+c]*p2[c] + wt[0][8+c]*p3[c] + wt[0][12+c]*xf[c];
        d1 += wt[1][c]*p1[c] + wt[1][4+c]*p2[c] + wt[1][8+c]*p3[c] + wt[1][12+c]*xf[c];
        d2 += wt[2][c]*p1[c] + wt[2][4+c]*p2[c] + wt[2][8+c]*p3[c] + wt[2][12+c]*xf[c];
        d3 += wt[3][c]*p1[c] + wt[3][4+c]*p2[c] + wt[3][8+c]*p3[c] + wt[3][12+c]*xf[c];
      }
      tail_track(d0, d1, d2, d3);
      sptr += 1; bptr += 1;
    }
  }
}

// ---------------- loss reduce: partials -> mean NLL ----------------
__global__ __launch_bounds__(256) void loss_kernel(const int* __restrict__ transes, int nT,
                                                   const float* __restrict__ bsc,
                                                   const float* __restrict__ ws,
                                                   float* __restrict__ out) {
  const int tid = threadIdx.x;
  const float* lossp = ws + O_LOSSP;
  __shared__ double red[256];
  double acc = 0.0;
  for (int t = tid; t < nT; t += 256) {
    const float* lp = lossp + (size_t)t * 128;
    float a0 = 0.f, a1 = 0.f;
    for (int w = 0; w < 64; ++w) { a0 += lp[2 * w]; a1 += lp[2 * w + 1]; }
    const float l0 = a0 + bsc[0], l1 = a1 + bsc[1];
    const float mx = fmaxf(l0, l1);
    acc += (double)(mx + logf(expf(l0 - mx) + expf(l1 - mx)) - (transes[t] ? l1 : l0));
  }
  red[tid] = acc;
  __syncthreads();
  for (int s = 128; s; s >>= 1) {
    if (tid < s) red[tid] += red[tid + s];
    __syncthreads();
  }
  if (tid == 0) out[0] = (float)(red[0] / (double)nT);
}

// ---------------- launch ----------------
extern "C" void kernel_launch(void* const* d_in, const int* in_sizes, int n_in,
                              void* d_out, int out_size, void* d_ws, size_t ws_size,
                              hipStream_t stream) {
  const int*   edu_words = (const int*)d_in[0];
  const int*   edu_poses = (const int*)d_in[1];
  const int*   transes   = (const int*)d_in[2];
  const float* word_emb  = (const float*)d_in[3];
  const float* pos_emb   = (const float*)d_in[4];
  const float* Wu  = (const float*)d_in[5];
  const float* bu  = (const float*)d_in[6];
  const float* Wb  = (const float*)d_in[7];
  const float* bb  = (const float*)d_in[8];
  const float* Wt  = (const float*)d_in[9];
  const float* bt  = (const float*)d_in[10];
  const float* Wp  = (const float*)d_in[11];
  const float* bp  = (const float*)d_in[12];
  const float* Wih = (const float*)d_in[13];
  const float* Whh = (const float*)d_in[14];
  const float* bih = (const float*)d_in[15];
  const float* bhh = (const float*)d_in[16];
  const float* Wc  = (const float*)d_in[17];
  const float* bc  = (const float*)d_in[18];
  const float* Wsc = (const float*)d_in[19];
  const float* bsc = (const float*)d_in[20];
  float* ws  = (float*)d_ws;
  float* out = (float*)d_out;
  int nT = in_sizes[2];

  hipLaunchKernelGGL(prep_kernel, dim3(256), dim3(256), 0, stream, Wu, Wb, Wt, ws);
  hipLaunchKernelGGL(encode_kernel, dim3(NEDU), dim3(256), 0, stream,
                     edu_words, edu_poses, word_emb, pos_emb, bu, bb, bt, ws);
  hipLaunchKernelGGL(proj_kernel, dim3(16, 8), dim3(256), 0, stream, Wp, bp, ws);

  void* args[] = { (void*)&transes, (void*)&nT, (void*)&Wih, (void*)&Whh, (void*)&bih,
                   (void*)&bhh, (void*)&Wc, (void*)&bc, (void*)&Wsc, (void*)&ws };
  hipLaunchCooperativeKernel((const void*)parse_kernel, dim3(NWG), dim3(256), args, 0, stream);

  hipLaunchKernelGGL(loss_kernel, dim3(1), dim3(256), 0, stream, transes, nT, bsc, ws, out);
}

// Round 8
// 8654.678 us; speedup vs baseline: 1.1613x; 1.1613x over previous
//
#include <hip/hip_runtime.h>
#include <math.h>

// ---------------- problem constants ----------------
#define NEDU  1024
#define LTOK  20
#define CW    330     // 300 word + 30 pos
#define HDIM  256
#define FEAT  930
#define MSLOT 1026    // N_EDUS + 2
#define NWG   32      // parse workgroups; WG bx owns h-indices 8bx..8bx+7
#define JW    8       // h-indices per WG

typedef unsigned long long u64;

// ---------------- workspace layout (32-bit word offsets) ----------------
#define O_WCATT 0
#define SZ_WCATT (330*600)
#define O_F     (O_WCATT + SZ_WCATT)
#define SZ_F    (NEDU*FEAT)
#define O_BUFH  (O_F + SZ_F)
#define SZ_BUF  (MSLOT*HDIM)
#define O_BUFC  (O_BUFH + SZ_BUF)
#define O_STKT  (O_BUFC + SZ_BUF)          // tagged stack_h [slot][j] u32
#define O_THT   (O_STKT + MSLOT*HDIM)      // tagged tracker h, 2 parities
#define O_RHT   (O_THT + 2*HDIM)           // tagged compose rh
#define O_LOSSP (O_RHT + HDIM)             // loss partials [2048][64] float
#define NZERO   ((MSLOT + 3) * HDIM)       // stkT + thT(2) + rhT -> zeros w/ tag 0

#define AG __HIP_MEMORY_SCOPE_AGENT
__device__ __forceinline__ u64 aload64(const u64* p) {
  return __hip_atomic_load(p, __ATOMIC_RELAXED, AG);
}
__device__ __forceinline__ void astore(unsigned* p, unsigned v) {
  __hip_atomic_store(p, v, __ATOMIC_RELAXED, AG);
}
__device__ __forceinline__ unsigned tagbits(float v, unsigned ver) {
  return (__float_as_uint(v) & ~3u) | (ver & 3u);
}
__device__ __forceinline__ bool tagok(u64 v, unsigned tag) {
  return (((unsigned)v & 3u) == tag) & (((unsigned)(v >> 32) & 3u) == tag);
}
__device__ __forceinline__ float sigm(float x) { return 1.f / (1.f + expf(-x)); }
__device__ __forceinline__ void unpack(u64 a, u64 b, float* x) {
  x[0] = __uint_as_float((unsigned)a); x[1] = __uint_as_float((unsigned)(a >> 32));
  x[2] = __uint_as_float((unsigned)b); x[3] = __uint_as_float((unsigned)(b >> 32));
}
// raw WG barrier: waits LDS ops only, NOT vmem stores (no vmcnt drain)
__device__ __forceinline__ void sync_lds() {
  asm volatile("s_waitcnt lgkmcnt(0)\n\ts_barrier" ::: "memory");
}
// spin-gather one tagged 256-vector: lane gets elements 4l..4l+3
__device__ __forceinline__ void gather1T(const unsigned* base, int lane, unsigned tag,
                                         float* x) {
  const u64* p = (const u64*)base + 2 * lane;
  for (int it = 0;; ++it) {
    const u64 a = aload64(p), b = aload64(p + 1);
    if (__ballot(tagok(a, tag) & tagok(b, tag)) == ~0ull) { unpack(a, b, x); return; }
    if (it > 48) __builtin_amdgcn_s_sleep(1);
  }
}
// combined retry for two tagged vectors
__device__ __forceinline__ void gather2T(const unsigned* b1, unsigned t1,
                                         const unsigned* b2, unsigned t2,
                                         int lane, float* x1, float* x2) {
  const u64* p1 = (const u64*)b1 + 2 * lane;
  const u64* p2 = (const u64*)b2 + 2 * lane;
  for (int it = 0;; ++it) {
    const u64 a = aload64(p1), b = aload64(p1 + 1);
    const u64 c = aload64(p2), d = aload64(p2 + 1);
    const bool ok = tagok(a, t1) & tagok(b, t1) & tagok(c, t2) & tagok(d, t2);
    if (__ballot(ok) == ~0ull) { unpack(a, b, x1); unpack(c, d, x2); return; }
    if (it > 48) __builtin_amdgcn_s_sleep(1);
  }
}

// ---------------- prep: weight transpose + zeroing ----------------
__global__ void prep_kernel(const float* __restrict__ Wu, const float* __restrict__ Wb,
                            const float* __restrict__ Wt, float* __restrict__ ws) {
  const int i0 = blockIdx.x * blockDim.x + threadIdx.x;
  const int st = gridDim.x * blockDim.x;
  for (int i = i0; i < SZ_WCATT; i += st) {
    const int k = i / 600, c = i - 600 * k;
    float v;
    if (c < 100)      v = Wu[c * 330 + k];
    else if (c < 300) { const int q = c - 100; v = Wb[(q % 100) * 660 + (q / 100) * 330 + k]; }
    else              { const int q = c - 300; v = Wt[(q % 100) * 990 + (q / 100) * 330 + k]; }
    ws[O_WCATT + i] = v;
  }
  unsigned* z = (unsigned*)ws + O_STKT;
  for (int i = i0; i < NZERO; i += st) z[i] = 0u;              // zeros with ver-0 tags
  for (int i = i0; i < 2 * HDIM; i += st) {                    // buf zero rows 1024,1025
    ws[O_BUFH + NEDU * HDIM + i] = 0.f;
    ws[O_BUFC + NEDU * HDIM + i] = 0.f;
  }
}

// ---------------- encode (unchanged) ----------------
__global__ __launch_bounds__(256) void encode_kernel(
    const int* __restrict__ edu_words, const int* __restrict__ edu_poses,
    const float* __restrict__ word_emb, const float* __restrict__ pos_emb,
    const float* __restrict__ bu, const float* __restrict__ bb,
    const float* __restrict__ bt, float* __restrict__ ws) {
  __shared__ __align__(16) float xlT[CW * LTOK];
  __shared__ float zl[300 * 21];
  __shared__ float convout[300];
  const int n = blockIdx.x, tid = threadIdx.x;
  const float* WcatT = ws + O_WCATT;

  for (int i = tid; i < LTOK * CW; i += 256) {
    const int l = i / CW, k = i - l * CW;
    float v;
    if (k < 300) v = word_emb[(size_t)edu_words[n * LTOK + l] * 300 + k];
    else         v = pos_emb[(size_t)edu_poses[n * LTOK + l] * 30 + (k - 300)];
    xlT[k * LTOK + l] = v;
  }
  __syncthreads();

  for (int f = tid; f < 300; f += 256) {
    float acc[LTOK];
#pragma unroll
    for (int l = 0; l < LTOK; ++l) acc[l] = 0.f;
    for (int k = 0; k < CW; ++k) {
      const float w = WcatT[k * 600 + f];
      const float4* xp = (const float4*)(xlT + k * LTOK);
      union { float4 v[5]; float s[20]; } xu;
      xu.v[0] = xp[0]; xu.v[1] = xp[1]; xu.v[2] = xp[2]; xu.v[3] = xp[3]; xu.v[4] = xp[4];
#pragma unroll
      for (int l = 0; l < LTOK; ++l) acc[l] += w * xu.s[l];
    }
#pragma unroll
    for (int l = 0; l < LTOK; ++l) zl[f * 21 + l] = acc[l];
  }
  __syncthreads();
  if (tid < 200) {
    float m;
    if (tid < 100) {
      const int f = tid; const float b = bu[f];
      m = zl[f * 21] + b;
      for (int l = 1; l < 20; ++l) m = fmaxf(m, zl[f * 21 + l] + b);
    } else {
      const int f = tid - 100; const float b = bb[f];
      const float* z0 = zl + (100 + f) * 21;
      const float* z1 = zl + (200 + f) * 21;
      m = z1[0] + b;
      for (int u = 1; u <= 19; ++u) m = fmaxf(m, z0[u - 1] + z1[u] + b);
      m = fmaxf(m, z0[19] + b);
    }
    convout[tid] = fmaxf(m, 0.f);
  }
  __syncthreads();

  for (int f = tid; f < 300; f += 256) {
    float acc[LTOK];
#pragma unroll
    for (int l = 0; l < LTOK; ++l) acc[l] = 0.f;
    for (int k = 0; k < CW; ++k) {
      const float w = WcatT[k * 600 + 300 + f];
      const float4* xp = (const float4*)(xlT + k * LTOK);
      union { float4 v[5]; float s[20]; } xu;
      xu.v[0] = xp[0]; xu.v[1] = xp[1]; xu.v[2] = xp[2]; xu.v[3] = xp[3]; xu.v[4] = xp[4];
#pragma unroll
      for (int l = 0; l < LTOK; ++l) acc[l] += w * xu.s[l];
    }
#pragma unroll
    for (int l = 0; l < LTOK; ++l) zl[f * 21 + l] = acc[l];
  }
  __syncthreads();
  if (tid < 100) {
    const int f = tid; const float b = bt[f];
    const float* z0 = zl + f * 21;
    const float* z1 = zl + (100 + f) * 21;
    const float* z2 = zl + (200 + f) * 21;
    float m = z2[0] + b;
    m = fmaxf(m, z1[0] + z2[1] + b);
    for (int u = 2; u <= 19; ++u) m = fmaxf(m, z0[u - 2] + z1[u - 1] + z2[u] + b);
    m = fmaxf(m, z0[18] + z1[19] + b);
    m = fmaxf(m, z0[19] + b);
    convout[200 + f] = fmaxf(m, 0.f);
  }
  __syncthreads();

  float* Fr = ws + O_F + (size_t)n * FEAT;
  for (int j = tid; j < FEAT; j += 256) {
    float v;
    if (j < 300)      v = xlT[j * LTOK + 0];
    else if (j < 600) v = xlT[(j - 300) * LTOK + 19];
    else if (j < 630) v = xlT[(j - 300) * LTOK + 0];
    else              v = convout[j - 630];
    Fr[j] = v;
  }
}

// ---------------- proj (unchanged) ----------------
__global__ __launch_bounds__(256) void proj_kernel(const float* __restrict__ Wp,
                                                   const float* __restrict__ bp,
                                                   float* __restrict__ ws) {
  __shared__ float As[64][17];
  __shared__ float Bs[64][17];
  const float* F = ws + O_F;
  float* bufh = ws + O_BUFH;
  float* bufc = ws + O_BUFC;
  const int tid = threadIdx.x;
  const int m0 = blockIdx.x * 64, n0 = blockIdx.y * 64;
  const int mm0 = (tid & 15) * 4, nn0 = (tid >> 4) * 4;
  float acc[4][4] = {{0.f}};
  for (int k0 = 0; k0 < FEAT; k0 += 16) {
    for (int i = tid; i < 64 * 16; i += 256) {
      const int mm = i >> 4, kk = i & 15;
      const int gk = k0 + kk;
      As[mm][kk] = (gk < FEAT) ? F[(size_t)(m0 + mm) * FEAT + gk] : 0.f;
      Bs[mm][kk] = (gk < FEAT) ? Wp[(size_t)(n0 + mm) * FEAT + gk] : 0.f;
    }
    __syncthreads();
#pragma unroll
    for (int kk = 0; kk < 16; ++kk) {
      float av[4], bv[4];
#pragma unroll
      for (int i = 0; i < 4; ++i) av[i] = As[mm0 + i][kk];
#pragma unroll
      for (int j = 0; j < 4; ++j) bv[j] = Bs[nn0 + j][kk];
#pragma unroll
      for (int i = 0; i < 4; ++i)
#pragma unroll
        for (int j = 0; j < 4; ++j) acc[i][j] += av[i] * bv[j];
    }
    __syncthreads();
  }
#pragma unroll
  for (int i = 0; i < 4; ++i) {
    const int m = m0 + mm0 + i;
#pragma unroll
    for (int j = 0; j < 4; ++j) {
      const int nn = n0 + nn0 + j;
      const float v = acc[i][j] + bp[nn];
      if (nn < 256) bufh[(size_t)m * 256 + nn] = v;
      else          bufc[(size_t)m * 256 + (nn - 256)] = v;
    }
  }
}

// ---------------- parse: R4 protocol, 32 WGs x 8 h-indices ----------------
__global__ __launch_bounds__(256, 1) void parse_kernel(
    const int* __restrict__ transes, int nT,
    const float* __restrict__ Wih, const float* __restrict__ Whh,
    const float* __restrict__ bih, const float* __restrict__ bhh,
    const float* __restrict__ Wc, const float* __restrict__ bc,
    const float* __restrict__ Wsc, float* __restrict__ ws) {
  const int tid = threadIdx.x;
  const int lane = tid & 63;
  const int wv = tid >> 6;
  const int bx = blockIdx.x;
  const int j0 = bx * JW;

  const float* bufh = ws + O_BUFH;
  const float* bufc = ws + O_BUFC;
  unsigned* stkT = (unsigned*)ws + O_STKT;
  unsigned* thT  = (unsigned*)ws + O_THT;
  unsigned* rhT  = (unsigned*)ws + O_RHT;
  float* lossp   = ws + O_LOSSP;

  __shared__ float sc_lds[MSLOT][JW];  // private stack-c for owned h-indices
  __shared__ unsigned vstk[MSLOT];     // per-slot version table (WG-uniform replay)
  __shared__ float g_lds[5 * JW];      // gate staging: index = gate*8 + jj
  __shared__ float part_lds[2 * JW];   // loss partial staging

  // ---- weight slices (element e = 4*lane + c) ----
  // track: wave wv owns gate wv for all 8 owned j's (rows rg = wv*256 + j0 + q)
  float wt[JW][16]; float bt_[JW];
#pragma unroll
  for (int q = 0; q < JW; ++q) {
    const int rg = wv * 256 + j0 + q;
#pragma unroll
    for (int blk = 0; blk < 3; ++blk) {
      const float4 w = *(const float4*)(Wih + (size_t)rg * 768 + blk * 256 + 4 * lane);
      wt[q][4 * blk + 0] = w.x; wt[q][4 * blk + 1] = w.y;
      wt[q][4 * blk + 2] = w.z; wt[q][4 * blk + 3] = w.w;
    }
    const float4 wh = *(const float4*)(Whh + (size_t)rg * 256 + 4 * lane);
    wt[q][12] = wh.x; wt[q][13] = wh.y; wt[q][14] = wh.z; wt[q][15] = wh.w;
    bt_[q] = bih[rg] + bhh[rg];
  }
  // compose: wave wv owns rows r = 10*wv+q (q<10); gate = r>>3, jj = r&7
  float wcm[10][12]; float bc_[10];
#pragma unroll
  for (int q = 0; q < 10; ++q) {
    const int r = 10 * wv + q, gate = r >> 3, jj = r & 7;
    const int rg = gate * 256 + j0 + jj;
#pragma unroll
    for (int blk = 0; blk < 3; ++blk) {
      const float4 w = *(const float4*)(Wc + (size_t)rg * 768 + blk * 256 + 4 * lane);
      wcm[q][4 * blk + 0] = w.x; wcm[q][4 * blk + 1] = w.y;
      wcm[q][4 * blk + 2] = w.z; wcm[q][4 * blk + 3] = w.w;
    }
    bc_[q] = bc[rg];
  }
  float ws0 = 0.f, ws1 = 0.f;
  if (tid < JW) { ws0 = Wsc[j0 + tid]; ws1 = Wsc[256 + j0 + tid]; }

  for (int i = tid; i < MSLOT; i += 256) vstk[i] = 0u;
  if (tid < JW) { sc_lds[0][tid] = 0.f; sc_lds[1][tid] = 0.f; }
  __syncthreads();

  unsigned V = 0, vrh = 0;
  int sptr = 2, bptr = 0;
  float tc_reg = 0.f;   // tracker c (tid<8)
  float rh_reg = 0.f;   // compose rh (tid<8)

  auto red8 = [&](float* d) {
#pragma unroll
    for (int off = 32; off; off >>= 1) {
#pragma unroll
      for (int q = 0; q < 8; ++q) d[q] += __shfl_down(d[q], off, 64);
    }
  };
  auto red10 = [&](float* d) {
#pragma unroll
    for (int off = 32; off; off >>= 1) {
#pragma unroll
      for (int q = 0; q < 10; ++q) d[q] += __shfl_down(d[q], off, 64);
    }
  };

  // dyn tail: gather fresh, add its FMAs, single reduce, barrier, fin, loss
  auto dyn_track = [&](const unsigned* fbase, unsigned ftag, int fblk, float* d) {
    float x[4];
    gather1T(fbase, lane, ftag, x);
#pragma unroll
    for (int q = 0; q < JW; ++q) {
#pragma unroll
      for (int c = 0; c < 4; ++c) d[q] += wt[q][4 * fblk + c] * x[c];
    }
    red8(d);
    if (lane == 0) {
#pragma unroll
      for (int q = 0; q < JW; ++q) g_lds[wv * JW + q] = d[q] + bt_[q];
    }
    sync_lds();
    if (tid < JW) {
      const int j = j0 + tid;
      const float gi = g_lds[tid], gf = g_lds[8 + tid], gg = g_lds[16 + tid],
                  go = g_lds[24 + tid];
      const float cn = sigm(gf) * tc_reg + sigm(gi) * tanhf(gg);
      tc_reg = cn;
      const float th = sigm(go) * tanhf(cn);
      astore(thT + ((V + 1) & 1) * HDIM + j, tagbits(th, V + 1));
      part_lds[tid] = ws0 * th; part_lds[JW + tid] = ws1 * th;
    }
    if (tid == 0) {
      float a0 = 0.f, a1 = 0.f;
#pragma unroll
      for (int q = 0; q < JW; ++q) { a0 += part_lds[q]; a1 += part_lds[JW + q]; }
      float* lp = lossp + (size_t)V * 64 + bx * 2;
      lp[0] = a0; lp[1] = a1;
    }
  };

  // track statics: d[q] = W·[p1;p2;p3] partial (blocks 0,1,2), unreduced
  auto stat3 = [&](const float* p1, const float* p2, const float* p3, float* d) {
#pragma unroll
    for (int q = 0; q < JW; ++q) {
      float a = 0.f;
#pragma unroll
      for (int c = 0; c < 4; ++c)
        a += wt[q][c] * p1[c] + wt[q][4 + c] * p2[c] + wt[q][8 + c] * p3[c];
      d[q] = a;
    }
  };

  // ---- initial track: statics stack[1],stack[0](v0),bufh[0]; fresh th(v0) ----
  {
    const float4 f3 = *(const float4*)(bufh + 4 * lane);
    float p1[4], p2[4];
    gather2T(stkT + HDIM, 0u, stkT, 0u, lane, p1, p2);
    const float p3[4] = { f3.x, f3.y, f3.z, f3.w };
    float d[JW];
    stat3(p1, p2, p3, d);
    dyn_track(thT, 0u, 3, d);
    sync_lds();
    V += 1;
  }

  for (int t = 0; t < nT; ++t) {
    const int tr = transes[t];
    if (tr) {
      // ==== compose: statics h1,h2 (combined gather); fresh th ====
      {
        float h1[4], h2[4], xth[4];
        gather2T(stkT + (size_t)(sptr - 1) * HDIM, vstk[sptr - 1] & 3,
                 stkT + (size_t)(sptr - 2) * HDIM, vstk[sptr - 2] & 3, lane, h1, h2);
        float e[10];
#pragma unroll
        for (int q = 0; q < 10; ++q) {
          float a = 0.f;
#pragma unroll
          for (int c = 0; c < 4; ++c)
            a += wcm[q][c] * h1[c] + wcm[q][4 + c] * h2[c];
          e[q] = a;
        }
        gather1T(thT + (V & 1) * HDIM, lane, V & 3, xth);
#pragma unroll
        for (int q = 0; q < 10; ++q) {
#pragma unroll
          for (int c = 0; c < 4; ++c) e[q] += wcm[q][8 + c] * xth[c];
        }
        red10(e);
        if (lane == 0) {
#pragma unroll
          for (int q = 0; q < 10; ++q) g_lds[10 * wv + q] = e[q] + bc_[q];
        }
        sync_lds();
        if (tid < JW) {
          const float ga = g_lds[tid], gi = g_lds[8 + tid], gf1 = g_lds[16 + tid],
                      gf2 = g_lds[24 + tid], go = g_lds[32 + tid];
          const float c1 = sc_lds[sptr - 1][tid];
          const float c2 = sc_lds[sptr - 2][tid];
          const float rc = tanhf(ga) * sigm(gi) + sigm(gf1) * c1 + sigm(gf2) * c2;
          sc_lds[sptr - 2][tid] = rc;
          rh_reg = sigm(go) * tanhf(rc);
          astore(rhT + j0 + tid, tagbits(rh_reg, vrh + 1));
        }
        vrh += 1;
        sync_lds();
      }
      // ==== trackR: statics stack[sptr-3], th(V) (combined); fresh rh ====
      {
        const float4 f3 = *(const float4*)(bufh + (size_t)bptr * HDIM + 4 * lane);
        float p2[4], xth[4];
        gather2T(stkT + (size_t)(sptr - 3) * HDIM, vstk[sptr - 3] & 3,
                 thT + (V & 1) * HDIM, V & 3, lane, p2, xth);
        const float p3[4] = { f3.x, f3.y, f3.z, f3.w };
        float d[JW];
#pragma unroll
        for (int q = 0; q < JW; ++q) {
          float a = 0.f;
#pragma unroll
          for (int c = 0; c < 4; ++c)
            a += wt[q][4 + c] * p2[c] + wt[q][8 + c] * p3[c] + wt[q][12 + c] * xth[c];
          d[q] = a;
        }
        // fresh rh gather with the deferred stack write inserted post-detect
        float xr[4];
        gather1T(rhT, lane, vrh & 3, xr);
        // rh(vrh) fully tagged => every WG finished compose reads of slot sptr-2
        const unsigned nv2 = vstk[sptr - 2] + 1;
        if (tid < JW) astore(stkT + (size_t)(sptr - 2) * HDIM + j0 + tid,
                             tagbits(rh_reg, nv2));
#pragma unroll
        for (int q = 0; q < JW; ++q) {
#pragma unroll
          for (int c = 0; c < 4; ++c) d[q] += wt[q][c] * xr[c];
        }
        red8(d);
        if (lane == 0) {
#pragma unroll
          for (int q = 0; q < JW; ++q) g_lds[wv * JW + q] = d[q] + bt_[q];
        }
        sync_lds();
        if (tid < JW) {
          const int j = j0 + tid;
          const float gi = g_lds[tid], gf = g_lds[8 + tid], gg = g_lds[16 + tid],
                      go = g_lds[24 + tid];
          const float cn = sigm(gf) * tc_reg + sigm(gi) * tanhf(gg);
          tc_reg = cn;
          const float th = sigm(go) * tanhf(cn);
          astore(thT + ((V + 1) & 1) * HDIM + j, tagbits(th, V + 1));
          part_lds[tid] = ws0 * th; part_lds[JW + tid] = ws1 * th;
        }
        if (tid == 0) {
          float a0 = 0.f, a1 = 0.f;
#pragma unroll
          for (int q = 0; q < JW; ++q) { a0 += part_lds[q]; a1 += part_lds[JW + q]; }
          float* lp = lossp + (size_t)V * 64 + bx * 2;
          lp[0] = a0; lp[1] = a1;
        }
        if (tid == 0) vstk[sptr - 2] = nv2;
        sync_lds();
        V += 1; sptr -= 1;
      }
    } else {
      // ==== trackS: early push; static stack[sptr-1]; fresh th ====
      const unsigned nv = vstk[sptr] + 1;
      if (tid < JW) {
        const int j = j0 + tid;
        astore(stkT + (size_t)sptr * HDIM + j, tagbits(bufh[(size_t)bptr * HDIM + j], nv));
        sc_lds[sptr][tid] = bufc[(size_t)bptr * HDIM + j];
      }
      const float4 f1 = *(const float4*)(bufh + (size_t)bptr * HDIM + 4 * lane);
      const float4 f3 = *(const float4*)(bufh + (size_t)(bptr + 1) * HDIM + 4 * lane);
      float p2[4];
      gather1T(stkT + (size_t)(sptr - 1) * HDIM, lane, vstk[sptr - 1] & 3, p2);
      const float p1[4] = { f1.x, f1.y, f1.z, f1.w };
      const float p3[4] = { f3.x, f3.y, f3.z, f3.w };
      float d[JW];
      stat3(p1, p2, p3, d);
      dyn_track(thT + (V & 1) * HDIM, V & 3, 3, d);
      if (tid == 0) vstk[sptr] = nv;
      sync_lds();
      V += 1; sptr += 1; bptr += 1;
    }
  }
}

// ---------------- loss reduce: partials -> mean NLL ----------------
__global__ __launch_bounds__(256) void loss_kernel(const int* __restrict__ transes, int nT,
                                                   const float* __restrict__ bsc,
                                                   const float* __restrict__ ws,
                                                   float* __restrict__ out) {
  const int tid = threadIdx.x;
  const float* lossp = ws + O_LOSSP;
  __shared__ double red[256];
  double acc = 0.0;
  for (int t = tid; t < nT; t += 256) {
    const float* lp = lossp + (size_t)t * 64;
    float a0 = 0.f, a1 = 0.f;
    for (int w = 0; w < NWG; ++w) { a0 += lp[2 * w]; a1 += lp[2 * w + 1]; }
    const float l0 = a0 + bsc[0], l1 = a1 + bsc[1];
    const float mx = fmaxf(l0, l1);
    acc += (double)(mx + logf(expf(l0 - mx) + expf(l1 - mx)) - (transes[t] ? l1 : l0));
  }
  red[tid] = acc;
  __syncthreads();
  for (int s = 128; s; s >>= 1) {
    if (tid < s) red[tid] += red[tid + s];
    __syncthreads();
  }
  if (tid == 0) out[0] = (float)(red[0] / (double)nT);
}

// ---------------- launch ----------------
extern "C" void kernel_launch(void* const* d_in, const int* in_sizes, int n_in,
                              void* d_out, int out_size, void* d_ws, size_t ws_size,
                              hipStream_t stream) {
  const int*   edu_words = (const int*)d_in[0];
  const int*   edu_poses = (const int*)d_in[1];
  const int*   transes   = (const int*)d_in[2];
  const float* word_emb  = (const float*)d_in[3];
  const float* pos_emb   = (const float*)d_in[4];
  const float* Wu  = (const float*)d_in[5];
  const float* bu  = (const float*)d_in[6];
  const float* Wb  = (const float*)d_in[7];
  const float* bb  = (const float*)d_in[8];
  const float* Wt  = (const float*)d_in[9];
  const float* bt  = (const float*)d_in[10];
  const float* Wp  = (const float*)d_in[11];
  const float* bp  = (const float*)d_in[12];
  const float* Wih = (const float*)d_in[13];
  const float* Whh = (const float*)d_in[14];
  const float* bih = (const float*)d_in[15];
  const float* bhh = (const float*)d_in[16];
  const float* Wc  = (const float*)d_in[17];
  const float* bc  = (const float*)d_in[18];
  const float* Wsc = (const float*)d_in[19];
  const float* bsc = (const float*)d_in[20];
  float* ws  = (float*)d_ws;
  float* out = (float*)d_out;
  int nT = in_sizes[2];

  hipLaunchKernelGGL(prep_kernel, dim3(256), dim3(256), 0, stream, Wu, Wb, Wt, ws);
  hipLaunchKernelGGL(encode_kernel, dim3(NEDU), dim3(256), 0, stream,
                     edu_words, edu_poses, word_emb, pos_emb, bu, bb, bt, ws);
  hipLaunchKernelGGL(proj_kernel, dim3(16, 8), dim3(256), 0, stream, Wp, bp, ws);

  void* args[] = { (void*)&transes, (void*)&nT, (void*)&Wih, (void*)&Whh, (void*)&bih,
                   (void*)&bhh, (void*)&Wc, (void*)&bc, (void*)&Wsc, (void*)&ws };
  hipLaunchCooperativeKernel((const void*)parse_kernel, dim3(NWG), dim3(256), args, 0, stream);

  hipLaunchKernelGGL(loss_kernel, dim3(1), dim3(256), 0, stream, transes, nT, bsc, ws, out);
}